// Round 7
// baseline (142.929 us; speedup 1.0000x reference)
//
#include <hip/hip_runtime.h>

typedef __bf16 bf16_t;
typedef __bf16 bf16x4 __attribute__((ext_vector_type(4)));
typedef __bf16 bf16x8 __attribute__((ext_vector_type(8)));
typedef float  f32x4  __attribute__((ext_vector_type(4)));

#define ASYNC_COPY16(gp, lp)                                                     \
  __builtin_amdgcn_global_load_lds(                                              \
      (const __attribute__((address_space(1))) void*)(gp),                       \
      (__attribute__((address_space(3))) void*)(lp), 16, 0, 0)

// ------------------------------------------------- prep: weights cvt + RMSNorm
// blocks [0,256) Wi, [256,512) Wo, [512,1536) Wsk, [1536, 1536+16384) rmsnorm
__global__ __launch_bounds__(256) void k_prep(const float* __restrict__ tokens,
                                              const float* __restrict__ norm_w,
                                              bf16_t* __restrict__ x,
                                              const float* __restrict__ W_in,
                                              bf16_t* __restrict__ Wi,
                                              const float* __restrict__ W_out,
                                              bf16_t* __restrict__ Wo,
                                              const float* __restrict__ W_skip,
                                              bf16_t* __restrict__ Wsk) {
  const int bid = blockIdx.x;
  const int tid = threadIdx.x;
  if (bid < 1536) {
    const float* s;
    bf16_t* d;
    int i;
    if (bid < 256)      { s = W_in;   d = Wi;  i = bid * 256 + tid; }
    else if (bid < 512) { s = W_out;  d = Wo;  i = (bid - 256) * 256 + tid; }
    else                { s = W_skip; d = Wsk; i = (bid - 512) * 256 + tid; }
    float4 v = ((const float4*)s)[i];
    bf16x4 o;
    o[0] = (bf16_t)v.x; o[1] = (bf16_t)v.y; o[2] = (bf16_t)v.z; o[3] = (bf16_t)v.w;
    ((bf16x4*)d)[i] = o;
    return;
  }
  const int row = bid - 1536;
  const size_t base = (size_t)row * 1024;
  float4 v = ((const float4*)(tokens + base))[tid];
  float ss = v.x * v.x + v.y * v.y + v.z * v.z + v.w * v.w;
#pragma unroll
  for (int off = 32; off > 0; off >>= 1) ss += __shfl_down(ss, off);
  __shared__ float sred[4];
  if ((tid & 63) == 0) sred[tid >> 6] = ss;
  __syncthreads();
  float tot = sred[0] + sred[1] + sred[2] + sred[3];
  float scale = rsqrtf(tot * (1.0f / 1024.0f) + 1e-4f);
  float4 wv = ((const float4*)norm_w)[tid];
  bf16x4 o;
  o[0] = (bf16_t)(v.x * scale * wv.x);
  o[1] = (bf16_t)(v.y * scale * wv.y);
  o[2] = (bf16_t)(v.z * scale * wv.z);
  o[3] = (bf16_t)(v.w * scale * wv.w);
  *(bf16x4*)(x + base + (size_t)tid * 4) = o;
}

// ------------------------------------------------------------------- GEMM1
// u[16384,256](bf16) = x @ W_in^T + b_in   (unchanged from R6)
__global__ __launch_bounds__(256, 4) void k_gemm1(const bf16_t* __restrict__ A,
                                                  const bf16_t* __restrict__ Bw,
                                                  const float* __restrict__ bias,
                                                  bf16_t* __restrict__ C) {
  constexpr int K = 1024, Nc = 256;
  __shared__ __align__(16) bf16_t sA[64 * 64];
  __shared__ __align__(16) bf16_t sB[64 * 64];
  const int tid = threadIdx.x;
  const int lane = tid & 63;
  const int w = tid >> 6;
  const int wm = w >> 1, wn = w & 1;

  const int bid = blockIdx.x;
  const int swz = (bid & 7) * 128 + (bid >> 3);
  const int bm = swz >> 2;
  const int bn = swz & 3;

  const int st_row = tid >> 3;
  const int st_col = ((tid & 7) ^ ((tid >> 3) & 7)) * 8;
  const int lds_off = tid * 8;

  f32x4 acc[2][2] = {};

  for (int k0 = 0; k0 < K; k0 += 64) {
#pragma unroll
    for (int j = 0; j < 2; ++j)
      ASYNC_COPY16(A + (size_t)(bm * 64 + j * 32 + st_row) * K + k0 + st_col,
                   &sA[j * 2048 + lds_off]);
#pragma unroll
    for (int j = 0; j < 2; ++j)
      ASYNC_COPY16(Bw + (size_t)(bn * 64 + j * 32 + st_row) * K + k0 + st_col,
                   &sB[j * 2048 + lds_off]);
    __syncthreads();

#pragma unroll
    for (int kk = 0; kk < 2; ++kk) {
      const int slot = ((kk * 4 + (lane >> 4)) ^ (lane & 7)) * 8;
      bf16x8 af[2], bfr[2];
#pragma unroll
      for (int m = 0; m < 2; ++m)
        af[m] = *(const bf16x8*)&sA[(wm * 32 + m * 16 + (lane & 15)) * 64 + slot];
#pragma unroll
      for (int n = 0; n < 2; ++n)
        bfr[n] = *(const bf16x8*)&sB[(wn * 32 + n * 16 + (lane & 15)) * 64 + slot];
#pragma unroll
      for (int m = 0; m < 2; ++m)
#pragma unroll
        for (int n = 0; n < 2; ++n)
          acc[m][n] = __builtin_amdgcn_mfma_f32_16x16x32_bf16(af[m], bfr[n],
                                                              acc[m][n], 0, 0, 0);
    }
    __syncthreads();
  }

#pragma unroll
  for (int n = 0; n < 2; ++n) {
    const int col = bn * 64 + wn * 32 + n * 16 + (lane & 15);
    const float bv = bias[col];
#pragma unroll
    for (int m = 0; m < 2; ++m) {
      const int rbase = bm * 64 + wm * 32 + m * 16 + (lane >> 4) * 4;
#pragma unroll
      for (int j = 0; j < 4; ++j)
        C[(size_t)(rbase + j) * Nc + col] = (bf16_t)(acc[m][n][j] + bv);
    }
  }
}

// --------------------------------------------------------------------- scan
__global__ __launch_bounds__(256) void k_scan(const bf16_t* __restrict__ u,
                                              const float* __restrict__ log_decay,
                                              bf16_t* __restrict__ states) {
  const int n = threadIdx.x;
  const int c = blockIdx.x;
  const int b = blockIdx.y;
  const float decay = 1.0f / (1.0f + __expf(-log_decay[n]));
  const bf16_t* up = u + (size_t)b * 4096 * 256 + n;
  bf16_t* sp = states + (size_t)b * 4096 * 256 + n;
  const int t0 = c * 64;
  const int tb = (c == 0) ? 0 : t0 - 64;
  const int te = t0 + 64;
  float state = 0.0f;
  for (int tblk = tb; tblk < te; tblk += 8) {
    float v[8];
#pragma unroll
    for (int q = 0; q < 8; ++q) v[q] = (float)up[(size_t)(tblk + q) * 256];
#pragma unroll
    for (int q = 0; q < 8; ++q) {
      state = fmaf(decay, state, v[q]);
      if (tblk + q >= t0) sp[(size_t)(tblk + q) * 256] = (bf16_t)state;
    }
  }
}

// -------------------------------------------------------------- fused GEMM2
// out = St@Wo^T (K=256) + X@Wsk^T (K=1024) + tokens + b_out + b_skip
// 256x256 tile, 8 waves (2Mx4N, wave 128x64), 2-dbuf 128KiB LDS.
// 4 phases per K-tile; stages for kt+2 issued at kt's q2 (B) / q3 (A);
// ONE vmcnt(8) per K-tile (8 gloads always in flight, never drained until
// tail). Raw s_barrier + zero-cost asm("":::"memory") compiler fences only —
// no sched_barrier, no asm lgkmcnt (compiler schedules ds_read waits).
// Safety: end-of-phase barriers bound wave lag to 1 phase; each stage's
// target region was last read >= 2 phases before the issue point; in-order
// vmcnt retirement => vmcnt(8) at q0 retires exactly kt's 8 loads.
__global__ __launch_bounds__(512, 2) void k_gemm2(const bf16_t* __restrict__ St,
                                                  const bf16_t* __restrict__ X,
                                                  const bf16_t* __restrict__ Wo,
                                                  const bf16_t* __restrict__ Wsk,
                                                  const float* __restrict__ tokens,
                                                  const float* __restrict__ b_out,
                                                  const float* __restrict__ b_skip,
                                                  float* __restrict__ out) {
  __shared__ __align__(16) bf16_t sA[2][2][128 * 64];  // [buf][half][row*64]
  __shared__ __align__(16) bf16_t sB[2][2][128 * 64];
  const int tid = threadIdx.x;
  const int lane = tid & 63;
  const int w = tid >> 6;     // 0..7
  const int wm = w >> 2;      // 0..1
  const int wn = w & 3;       // 0..3

  const int bid = blockIdx.x;
  const int swz = (bid & 7) * 32 + (bid >> 3);
  const int bm = swz >> 2;    // 0..63
  const int bn = swz & 3;     // 0..3

  // stage geometry: 2 gloads per half (inst j covers rows j*64 + tid>>3);
  // linear LDS dest; global col slot pre-XORed by row&7 (involution)
  const int st_row = tid >> 3;                              // 0..63 (+ j*64)
  const int st_scol = ((tid & 7) ^ ((tid >> 3) & 7)) * 8;   // elements
  const int st_off = tid * 8;                               // elements (+ j*4096)

  f32x4 acc[8][4] = {};

  auto srcA = [&](int kt, int& ld, int& kb) -> const bf16_t* {
    if (kt < 4) { ld = 256;  kb = kt * 64;       return St; }
    else        { ld = 1024; kb = (kt - 4) * 64; return X;  }
  };
  auto srcB = [&](int kt, int& ld, int& kb) -> const bf16_t* {
    if (kt < 4) { ld = 256;  kb = kt * 64;       return Wo;  }
    else        { ld = 1024; kb = (kt - 4) * 64; return Wsk; }
  };

  auto stageA = [&](int kt) {
    int ld, kb;
    const bf16_t* s = srcA(kt, ld, kb);
#pragma unroll
    for (int h = 0; h < 2; ++h) {
      const bf16_t* g = s + (size_t)(bm * 256 + h * 128 + st_row) * ld + kb + st_scol;
      bf16_t* l = &sA[kt & 1][h][st_off];
      ASYNC_COPY16(g, l);
      ASYNC_COPY16(g + (size_t)64 * ld, l + 4096);
    }
  };
  auto stageB = [&](int kt) {
    int ld, kb;
    const bf16_t* s = srcB(kt, ld, kb);
#pragma unroll
    for (int h = 0; h < 2; ++h) {
      const bf16_t* g = s + (size_t)(bn * 256 + h * 128 + st_row) * ld + kb + st_scol;
      bf16_t* l = &sB[kt & 1][h][st_off];
      ASYNC_COPY16(g, l);
      ASYNC_COPY16(g + (size_t)64 * ld, l + 4096);
    }
  };

  // prologue: kt0 fully, then kt1 fully (issue order => in-order retirement)
  stageA(0); stageB(0);
  stageA(1); stageB(1);

  const int brow0 = (wn & 1) * 64;   // row base within this wave's B-half

  for (int kt = 0; kt < 20; ++kt) {
    const bf16_t* a = &sA[kt & 1][wm][0];
    const bf16_t* b = &sB[kt & 1][wn >> 1][0];

    bf16x8 af[4][2], bf0[2][2], bf1[2][2];

    // ---- q0: consume-wait + reads af[m0-3], bfr[n0-1]; MFMA m0-3 x n0-1
    if (kt < 19) asm volatile("s_waitcnt vmcnt(8)" ::: "memory");
    else         asm volatile("s_waitcnt vmcnt(0)" ::: "memory");
    __builtin_amdgcn_s_barrier();
    asm volatile("" ::: "memory");
#pragma unroll
    for (int m = 0; m < 4; ++m)
#pragma unroll
      for (int kk = 0; kk < 2; ++kk) {
        const int slot = ((kk * 4 + (lane >> 4)) ^ (lane & 7)) * 8;
        af[m][kk] = *(const bf16x8*)&a[(m * 16 + (lane & 15)) * 64 + slot];
      }
#pragma unroll
    for (int n = 0; n < 2; ++n)
#pragma unroll
      for (int kk = 0; kk < 2; ++kk) {
        const int slot = ((kk * 4 + (lane >> 4)) ^ (lane & 7)) * 8;
        bf0[n][kk] = *(const bf16x8*)&b[(brow0 + n * 16 + (lane & 15)) * 64 + slot];
      }
    __builtin_amdgcn_s_setprio(1);
#pragma unroll
    for (int m = 0; m < 4; ++m)
#pragma unroll
      for (int n = 0; n < 2; ++n)
#pragma unroll
        for (int kk = 0; kk < 2; ++kk)
          acc[m][n] = __builtin_amdgcn_mfma_f32_16x16x32_bf16(af[m][kk], bf0[n][kk],
                                                              acc[m][n], 0, 0, 0);
    __builtin_amdgcn_s_setprio(0);
    __builtin_amdgcn_s_barrier();
    asm volatile("" ::: "memory");

    // ---- q1: reads bfr[n2-3]; MFMA m0-3 x n2-3
#pragma unroll
    for (int n = 0; n < 2; ++n)
#pragma unroll
      for (int kk = 0; kk < 2; ++kk) {
        const int slot = ((kk * 4 + (lane >> 4)) ^ (lane & 7)) * 8;
        bf1[n][kk] = *(const bf16x8*)&b[(brow0 + (2 + n) * 16 + (lane & 15)) * 64 + slot];
      }
    __builtin_amdgcn_s_setprio(1);
#pragma unroll
    for (int m = 0; m < 4; ++m)
#pragma unroll
      for (int n = 0; n < 2; ++n)
#pragma unroll
        for (int kk = 0; kk < 2; ++kk)
          acc[m][2 + n] = __builtin_amdgcn_mfma_f32_16x16x32_bf16(af[m][kk], bf1[n][kk],
                                                                  acc[m][2 + n], 0, 0, 0);
    __builtin_amdgcn_s_setprio(0);
    __builtin_amdgcn_s_barrier();
    asm volatile("" ::: "memory");

    // ---- q2: stage B(kt+2); reads af[m4-7] (reuse regs); MFMA m4-7 x n2-3
    if (kt < 18) stageB(kt + 2);
#pragma unroll
    for (int m = 0; m < 4; ++m)
#pragma unroll
      for (int kk = 0; kk < 2; ++kk) {
        const int slot = ((kk * 4 + (lane >> 4)) ^ (lane & 7)) * 8;
        af[m][kk] = *(const bf16x8*)&a[((4 + m) * 16 + (lane & 15)) * 64 + slot];
      }
    __builtin_amdgcn_s_setprio(1);
#pragma unroll
    for (int m = 0; m < 4; ++m)
#pragma unroll
      for (int n = 0; n < 2; ++n)
#pragma unroll
        for (int kk = 0; kk < 2; ++kk)
          acc[4 + m][2 + n] = __builtin_amdgcn_mfma_f32_16x16x32_bf16(af[m][kk], bf1[n][kk],
                                                                      acc[4 + m][2 + n], 0, 0, 0);
    __builtin_amdgcn_s_setprio(0);
    __builtin_amdgcn_s_barrier();
    asm volatile("" ::: "memory");

    // ---- q3: stage A(kt+2); no reads; MFMA m4-7 x n0-1 (kept bf0)
    if (kt < 18) stageA(kt + 2);
    __builtin_amdgcn_s_setprio(1);
#pragma unroll
    for (int m = 0; m < 4; ++m)
#pragma unroll
      for (int n = 0; n < 2; ++n)
#pragma unroll
        for (int kk = 0; kk < 2; ++kk)
          acc[4 + m][n] = __builtin_amdgcn_mfma_f32_16x16x32_bf16(af[m][kk], bf0[n][kk],
                                                                  acc[4 + m][n], 0, 0, 0);
    __builtin_amdgcn_s_setprio(0);
    __builtin_amdgcn_s_barrier();
    asm volatile("" ::: "memory");
  }

  // epilogue: C/D layout col=lane&15, row=(lane>>4)*4+j
  const int row0 = bm * 256 + wm * 128 + (lane >> 4) * 4;
  const int col0 = bn * 256 + wn * 64 + (lane & 15);
#pragma unroll
  for (int n = 0; n < 4; ++n) {
    const int col = col0 + n * 16;
    const float bv = b_out[col] + b_skip[col];
#pragma unroll
    for (int m = 0; m < 8; ++m) {
      const int r = row0 + m * 16;
#pragma unroll
      for (int j = 0; j < 4; ++j) {
        const size_t idx = (size_t)(r + j) * 1024 + col;
        out[idx] = acc[m][n][j] + tokens[idx] + bv;
      }
    }
  }
}

// ------------------------------------------------------------------ launch
extern "C" void kernel_launch(void* const* d_in, const int* in_sizes, int n_in,
                              void* d_out, int out_size, void* d_ws, size_t ws_size,
                              hipStream_t stream) {
  const float* tokens  = (const float*)d_in[0];
  const float* norm_w  = (const float*)d_in[1];
  const float* W_in    = (const float*)d_in[2];
  const float* b_in    = (const float*)d_in[3];
  const float* W_out   = (const float*)d_in[4];
  const float* b_out   = (const float*)d_in[5];
  const float* W_skip  = (const float*)d_in[6];
  const float* b_skip  = (const float*)d_in[7];
  const float* log_dec = (const float*)d_in[8];
  float* out = (float*)d_out;

  char* w = (char*)d_ws;
  bf16_t* xb  = (bf16_t*)(w);                       // 32 MiB
  bf16_t* u   = (bf16_t*)(w + 33554432ull);         //  8 MiB
  bf16_t* st  = (bf16_t*)(w + 41943040ull);         //  8 MiB
  bf16_t* Wi  = (bf16_t*)(w + 50331648ull);
  bf16_t* Wo  = (bf16_t*)(w + 50855936ull);
  bf16_t* Wsk = (bf16_t*)(w + 51380224ull);

  k_prep<<<dim3(17920), 256, 0, stream>>>(tokens, norm_w, xb, W_in, Wi,
                                          W_out, Wo, W_skip, Wsk);

  k_gemm1<<<dim3(1024), 256, 0, stream>>>(xb, Wi, b_in, u);

  k_scan<<<dim3(64, 4), 256, 0, stream>>>(u, log_dec, st);

  k_gemm2<<<dim3(256), 512, 0, stream>>>(st, xb, Wo, Wsk, tokens, b_out,
                                         b_skip, out);
}

// Round 8
// 129.927 us; speedup vs baseline: 1.1001x; 1.1001x over previous
//
#include <hip/hip_runtime.h>

typedef __bf16 bf16_t;
typedef __bf16 bf16x4 __attribute__((ext_vector_type(4)));
typedef __bf16 bf16x8 __attribute__((ext_vector_type(8)));
typedef float  f32x4  __attribute__((ext_vector_type(4)));

#define ASYNC_COPY16(gp, lp)                                                     \
  __builtin_amdgcn_global_load_lds(                                              \
      (const __attribute__((address_space(1))) void*)(gp),                       \
      (__attribute__((address_space(3))) void*)(lp), 16, 0, 0)

// ------------------------------------------------- prep: weights cvt + RMSNorm
// blocks [0,256) Wi, [256,512) Wo, [512,1536) Wsk, [1536, 1536+16384) rmsnorm
__global__ __launch_bounds__(256) void k_prep(const float* __restrict__ tokens,
                                              const float* __restrict__ norm_w,
                                              bf16_t* __restrict__ x,
                                              const float* __restrict__ W_in,
                                              bf16_t* __restrict__ Wi,
                                              const float* __restrict__ W_out,
                                              bf16_t* __restrict__ Wo,
                                              const float* __restrict__ W_skip,
                                              bf16_t* __restrict__ Wsk) {
  const int bid = blockIdx.x;
  const int tid = threadIdx.x;
  if (bid < 1536) {
    const float* s;
    bf16_t* d;
    int i;
    if (bid < 256)      { s = W_in;   d = Wi;  i = bid * 256 + tid; }
    else if (bid < 512) { s = W_out;  d = Wo;  i = (bid - 256) * 256 + tid; }
    else                { s = W_skip; d = Wsk; i = (bid - 512) * 256 + tid; }
    float4 v = ((const float4*)s)[i];
    bf16x4 o;
    o[0] = (bf16_t)v.x; o[1] = (bf16_t)v.y; o[2] = (bf16_t)v.z; o[3] = (bf16_t)v.w;
    ((bf16x4*)d)[i] = o;
    return;
  }
  const int row = bid - 1536;
  const size_t base = (size_t)row * 1024;
  float4 v = ((const float4*)(tokens + base))[tid];
  float ss = v.x * v.x + v.y * v.y + v.z * v.z + v.w * v.w;
#pragma unroll
  for (int off = 32; off > 0; off >>= 1) ss += __shfl_down(ss, off);
  __shared__ float sred[4];
  if ((tid & 63) == 0) sred[tid >> 6] = ss;
  __syncthreads();
  float tot = sred[0] + sred[1] + sred[2] + sred[3];
  float scale = rsqrtf(tot * (1.0f / 1024.0f) + 1e-4f);
  float4 wv = ((const float4*)norm_w)[tid];
  bf16x4 o;
  o[0] = (bf16_t)(v.x * scale * wv.x);
  o[1] = (bf16_t)(v.y * scale * wv.y);
  o[2] = (bf16_t)(v.z * scale * wv.z);
  o[3] = (bf16_t)(v.w * scale * wv.w);
  *(bf16x4*)(x + base + (size_t)tid * 4) = o;
}

// ------------------------------------------------------------------- GEMM1
// u[16384,256](bf16) = x @ W_in^T + b_in
// 128x64 tile, BK=64, 4 waves (2Mx2N, wave 64x32), grid (128,4)=512 blocks
// (2 blocks/CU), compiler-scheduled m97 structure, involution swizzle.
__global__ __launch_bounds__(256, 2) void k_gemm1(const bf16_t* __restrict__ A,
                                                  const bf16_t* __restrict__ Bw,
                                                  const float* __restrict__ bias,
                                                  bf16_t* __restrict__ C) {
  constexpr int K = 1024, Nc = 256;
  __shared__ __align__(16) bf16_t sA[128 * 64];
  __shared__ __align__(16) bf16_t sB[64 * 64];
  const int tid = threadIdx.x;
  const int lane = tid & 63;
  const int w = tid >> 6;
  const int wm = w >> 1, wn = w & 1;   // wave tile 64(M) x 32(N)

  // 512 blocks: XCD-contiguous, same-bm grouped (A-panel L2 reuse)
  const int bid = blockIdx.x;
  const int swz = (bid & 7) * 64 + (bid >> 3);
  const int bm = swz >> 2;   // 0..127
  const int bn = swz & 3;    // 0..3

  const int st_row = tid >> 3;                               // 0..31 (+ it*32)
  const int st_col = ((tid & 7) ^ ((tid >> 3) & 7)) * 8;     // involution slot
  const int lds_off = tid * 8;                               // (+ it*2048)

  f32x4 acc[4][2] = {};

  for (int k0 = 0; k0 < K; k0 += 64) {
#pragma unroll
    for (int it = 0; it < 4; ++it)
      ASYNC_COPY16(A + (size_t)(bm * 128 + it * 32 + st_row) * K + k0 + st_col,
                   &sA[it * 2048 + lds_off]);
#pragma unroll
    for (int it = 0; it < 2; ++it)
      ASYNC_COPY16(Bw + (size_t)(bn * 64 + it * 32 + st_row) * K + k0 + st_col,
                   &sB[it * 2048 + lds_off]);
    __syncthreads();   // compiler emits the vmcnt(0) drain

#pragma unroll
    for (int kk = 0; kk < 2; ++kk) {
      const int slot = ((kk * 4 + (lane >> 4)) ^ (lane & 7)) * 8;
      bf16x8 af[4], bfr[2];
#pragma unroll
      for (int m = 0; m < 4; ++m)
        af[m] = *(const bf16x8*)&sA[(wm * 64 + m * 16 + (lane & 15)) * 64 + slot];
#pragma unroll
      for (int n = 0; n < 2; ++n)
        bfr[n] = *(const bf16x8*)&sB[(wn * 32 + n * 16 + (lane & 15)) * 64 + slot];
#pragma unroll
      for (int m = 0; m < 4; ++m)
#pragma unroll
        for (int n = 0; n < 2; ++n)
          acc[m][n] = __builtin_amdgcn_mfma_f32_16x16x32_bf16(af[m], bfr[n],
                                                              acc[m][n], 0, 0, 0);
    }
    __syncthreads();
  }

#pragma unroll
  for (int n = 0; n < 2; ++n) {
    const int col = bn * 64 + wn * 32 + n * 16 + (lane & 15);
    const float bv = bias[col];
#pragma unroll
    for (int m = 0; m < 4; ++m) {
      const int rbase = bm * 128 + wm * 64 + m * 16 + (lane >> 4) * 4;
#pragma unroll
      for (int j = 0; j < 4; ++j)
        C[(size_t)(rbase + j) * Nc + col] = (bf16_t)(acc[m][n][j] + bv);
    }
  }
}

// --------------------------------------------------------------------- scan
__global__ __launch_bounds__(256) void k_scan(const bf16_t* __restrict__ u,
                                              const float* __restrict__ log_decay,
                                              bf16_t* __restrict__ states) {
  const int n = threadIdx.x;
  const int c = blockIdx.x;
  const int b = blockIdx.y;
  const float decay = 1.0f / (1.0f + __expf(-log_decay[n]));
  const bf16_t* up = u + (size_t)b * 4096 * 256 + n;
  bf16_t* sp = states + (size_t)b * 4096 * 256 + n;
  const int t0 = c * 64;
  const int tb = (c == 0) ? 0 : t0 - 64;
  const int te = t0 + 64;
  float state = 0.0f;
  for (int tblk = tb; tblk < te; tblk += 8) {
    float v[8];
#pragma unroll
    for (int q = 0; q < 8; ++q) v[q] = (float)up[(size_t)(tblk + q) * 256];
#pragma unroll
    for (int q = 0; q < 8; ++q) {
      state = fmaf(decay, state, v[q]);
      if (tblk + q >= t0) sp[(size_t)(tblk + q) * 256] = (bf16_t)state;
    }
  }
}

// -------------------------------------------------------------- fused GEMM2
// out = St@Wo^T (K=256) + X@Wsk^T (K=1024) + tokens + b_out + b_skip
// R6 winner, verbatim: m97-faithful 128x128, 4 waves, single-buffer 32 KiB,
// compiler-scheduled, plain __syncthreads, involution swizzle, 1024 blocks
// (4/CU — inter-block TLP covers the barrier drain; m114 mechanism).
__global__ __launch_bounds__(256) void k_gemm2(const bf16_t* __restrict__ St,
                                               const bf16_t* __restrict__ X,
                                               const bf16_t* __restrict__ Wo,
                                               const bf16_t* __restrict__ Wsk,
                                               const float* __restrict__ tokens,
                                               const float* __restrict__ b_out,
                                               const float* __restrict__ b_skip,
                                               float* __restrict__ out) {
  __shared__ __align__(16) bf16_t sA[128 * 64];
  __shared__ __align__(16) bf16_t sB[128 * 64];
  const int tid = threadIdx.x;
  const int lane = tid & 63;
  const int w = tid >> 6;
  const int wm = w >> 1, wn = w & 1;

  const int bid = blockIdx.x;
  const int swz = (bid & 7) * 128 + (bid >> 3);
  const int bm = swz >> 3;    // 0..127
  const int bn = swz & 7;     // 0..7

  const int st_row = tid >> 3;
  const int st_col = ((tid & 7) ^ ((tid >> 3) & 7)) * 8;
  const int lds_off = tid * 8;

  f32x4 acc[4][4] = {};

  for (int kt = 0; kt < 20; ++kt) {
    const bf16_t* Ab;
    const bf16_t* Bb;
    int ld, kb;
    if (kt < 4) { Ab = St; Bb = Wo;  ld = 256;  kb = kt * 64; }
    else        { Ab = X;  Bb = Wsk; ld = 1024; kb = (kt - 4) * 64; }
#pragma unroll
    for (int it = 0; it < 4; ++it)
      ASYNC_COPY16(Ab + (size_t)(bm * 128 + it * 32 + st_row) * ld + kb + st_col,
                   &sA[it * 2048 + lds_off]);
#pragma unroll
    for (int it = 0; it < 4; ++it)
      ASYNC_COPY16(Bb + (size_t)(bn * 128 + it * 32 + st_row) * ld + kb + st_col,
                   &sB[it * 2048 + lds_off]);
    __syncthreads();

#pragma unroll
    for (int kk = 0; kk < 2; ++kk) {
      const int slot = ((kk * 4 + (lane >> 4)) ^ (lane & 7)) * 8;
      bf16x8 af[4], bfr[4];
#pragma unroll
      for (int m = 0; m < 4; ++m)
        af[m] = *(const bf16x8*)&sA[(wm * 64 + m * 16 + (lane & 15)) * 64 + slot];
#pragma unroll
      for (int n = 0; n < 4; ++n)
        bfr[n] = *(const bf16x8*)&sB[(wn * 64 + n * 16 + (lane & 15)) * 64 + slot];
#pragma unroll
      for (int m = 0; m < 4; ++m)
#pragma unroll
        for (int n = 0; n < 4; ++n)
          acc[m][n] = __builtin_amdgcn_mfma_f32_16x16x32_bf16(af[m], bfr[n],
                                                              acc[m][n], 0, 0, 0);
    }
    __syncthreads();
  }

#pragma unroll
  for (int n = 0; n < 4; ++n) {
    const int col = bn * 128 + wn * 64 + n * 16 + (lane & 15);
    const float bv = b_out[col] + b_skip[col];
#pragma unroll
    for (int m = 0; m < 4; ++m) {
      const int rbase = bm * 128 + wm * 64 + m * 16 + (lane >> 4) * 4;
#pragma unroll
      for (int j = 0; j < 4; ++j) {
        const size_t idx = (size_t)(rbase + j) * 1024 + col;
        out[idx] = acc[m][n][j] + tokens[idx] + bv;
      }
    }
  }
}

// ------------------------------------------------------------------ launch
extern "C" void kernel_launch(void* const* d_in, const int* in_sizes, int n_in,
                              void* d_out, int out_size, void* d_ws, size_t ws_size,
                              hipStream_t stream) {
  const float* tokens  = (const float*)d_in[0];
  const float* norm_w  = (const float*)d_in[1];
  const float* W_in    = (const float*)d_in[2];
  const float* b_in    = (const float*)d_in[3];
  const float* W_out   = (const float*)d_in[4];
  const float* b_out   = (const float*)d_in[5];
  const float* W_skip  = (const float*)d_in[6];
  const float* b_skip  = (const float*)d_in[7];
  const float* log_dec = (const float*)d_in[8];
  float* out = (float*)d_out;

  char* w = (char*)d_ws;
  bf16_t* xb  = (bf16_t*)(w);                       // 32 MiB
  bf16_t* u   = (bf16_t*)(w + 33554432ull);         //  8 MiB
  bf16_t* st  = (bf16_t*)(w + 41943040ull);         //  8 MiB
  bf16_t* Wi  = (bf16_t*)(w + 50331648ull);
  bf16_t* Wo  = (bf16_t*)(w + 50855936ull);
  bf16_t* Wsk = (bf16_t*)(w + 51380224ull);

  k_prep<<<dim3(17920), 256, 0, stream>>>(tokens, norm_w, xb, W_in, Wi,
                                          W_out, Wo, W_skip, Wsk);

  k_gemm1<<<dim3(512), 256, 0, stream>>>(xb, Wi, b_in, u);

  k_scan<<<dim3(64, 4), 256, 0, stream>>>(u, log_dec, st);

  k_gemm2<<<dim3(1024), 256, 0, stream>>>(st, xb, Wo, Wsk, tokens, b_out,
                                          b_skip, out);
}

// Round 9
// 127.104 us; speedup vs baseline: 1.1245x; 1.0222x over previous
//
#include <hip/hip_runtime.h>

typedef __bf16 bf16_t;
typedef __bf16 bf16x4 __attribute__((ext_vector_type(4)));
typedef __bf16 bf16x8 __attribute__((ext_vector_type(8)));
typedef float  f32x4  __attribute__((ext_vector_type(4)));

#define ASYNC_COPY16(gp, lp)                                                     \
  __builtin_amdgcn_global_load_lds(                                              \
      (const __attribute__((address_space(1))) void*)(gp),                       \
      (__attribute__((address_space(3))) void*)(lp), 16, 0, 0)

// ------------------------------------------------- prep: weights cvt + RMSNorm
// blocks [0,256) Wi, [256,512) Wo, [512,1536) Wsk,
// [1536, 1536+4096): rmsnorm, wave-per-row (4 rows/block, no LDS/barrier)
__global__ __launch_bounds__(256) void k_prep(const float* __restrict__ tokens,
                                              const float* __restrict__ norm_w,
                                              bf16_t* __restrict__ x,
                                              const float* __restrict__ W_in,
                                              bf16_t* __restrict__ Wi,
                                              const float* __restrict__ W_out,
                                              bf16_t* __restrict__ Wo,
                                              const float* __restrict__ W_skip,
                                              bf16_t* __restrict__ Wsk) {
  const int bid = blockIdx.x;
  const int tid = threadIdx.x;
  if (bid < 1536) {
    const float* s;
    bf16_t* d;
    int i;
    if (bid < 256)      { s = W_in;   d = Wi;  i = bid * 256 + tid; }
    else if (bid < 512) { s = W_out;  d = Wo;  i = (bid - 256) * 256 + tid; }
    else                { s = W_skip; d = Wsk; i = (bid - 512) * 256 + tid; }
    float4 v = ((const float4*)s)[i];
    bf16x4 o;
    o[0] = (bf16_t)v.x; o[1] = (bf16_t)v.y; o[2] = (bf16_t)v.z; o[3] = (bf16_t)v.w;
    ((bf16x4*)d)[i] = o;
    return;
  }
  // wave-per-row RMSNorm: 4 waves/block, 1 row each; lane covers float4 slots
  // {lane, 64+lane, 128+lane, 192+lane} (wave reads 1 KB contiguous per iter)
  const int row = (bid - 1536) * 4 + (tid >> 6);
  const int lane = tid & 63;
  const size_t base = (size_t)row * 1024;
  const float4* tp = (const float4*)(tokens + base);
  float4 v[4];
  float ss = 0.0f;
#pragma unroll
  for (int i = 0; i < 4; ++i) {
    v[i] = tp[i * 64 + lane];
    ss += v[i].x * v[i].x + v[i].y * v[i].y + v[i].z * v[i].z + v[i].w * v[i].w;
  }
#pragma unroll
  for (int off = 32; off > 0; off >>= 1) ss += __shfl_xor(ss, off);
  const float scale = rsqrtf(ss * (1.0f / 1024.0f) + 1e-4f);
  bf16x4* xp = (bf16x4*)(x + base);
#pragma unroll
  for (int i = 0; i < 4; ++i) {
    float4 wv = ((const float4*)norm_w)[i * 64 + lane];
    bf16x4 o;
    o[0] = (bf16_t)(v[i].x * scale * wv.x);
    o[1] = (bf16_t)(v[i].y * scale * wv.y);
    o[2] = (bf16_t)(v[i].z * scale * wv.z);
    o[3] = (bf16_t)(v[i].w * scale * wv.w);
    xp[i * 64 + lane] = o;
  }
}

// ------------------------------------------------------------------- GEMM1
// u[16384,256](bf16) = x @ W_in^T + b_in
// 64x64 tile, BK=64, 4 waves (2x2, wave=32x32), grid 1024 -> 4 blocks/CU (TLP)
// (R6 config, evidence-based revert from R8's 128x64)
__global__ __launch_bounds__(256, 4) void k_gemm1(const bf16_t* __restrict__ A,
                                                  const bf16_t* __restrict__ Bw,
                                                  const float* __restrict__ bias,
                                                  bf16_t* __restrict__ C) {
  constexpr int K = 1024, Nc = 256;
  __shared__ __align__(16) bf16_t sA[64 * 64];
  __shared__ __align__(16) bf16_t sB[64 * 64];
  const int tid = threadIdx.x;
  const int lane = tid & 63;
  const int w = tid >> 6;
  const int wm = w >> 1, wn = w & 1;

  const int bid = blockIdx.x;
  const int swz = (bid & 7) * 128 + (bid >> 3);
  const int bm = swz >> 2;
  const int bn = swz & 3;

  const int st_row = tid >> 3;
  const int st_col = ((tid & 7) ^ ((tid >> 3) & 7)) * 8;
  const int lds_off = tid * 8;

  f32x4 acc[2][2] = {};

  for (int k0 = 0; k0 < K; k0 += 64) {
#pragma unroll
    for (int j = 0; j < 2; ++j)
      ASYNC_COPY16(A + (size_t)(bm * 64 + j * 32 + st_row) * K + k0 + st_col,
                   &sA[j * 2048 + lds_off]);
#pragma unroll
    for (int j = 0; j < 2; ++j)
      ASYNC_COPY16(Bw + (size_t)(bn * 64 + j * 32 + st_row) * K + k0 + st_col,
                   &sB[j * 2048 + lds_off]);
    __syncthreads();

#pragma unroll
    for (int kk = 0; kk < 2; ++kk) {
      const int slot = ((kk * 4 + (lane >> 4)) ^ (lane & 7)) * 8;
      bf16x8 af[2], bfr[2];
#pragma unroll
      for (int m = 0; m < 2; ++m)
        af[m] = *(const bf16x8*)&sA[(wm * 32 + m * 16 + (lane & 15)) * 64 + slot];
#pragma unroll
      for (int n = 0; n < 2; ++n)
        bfr[n] = *(const bf16x8*)&sB[(wn * 32 + n * 16 + (lane & 15)) * 64 + slot];
#pragma unroll
      for (int m = 0; m < 2; ++m)
#pragma unroll
        for (int n = 0; n < 2; ++n)
          acc[m][n] = __builtin_amdgcn_mfma_f32_16x16x32_bf16(af[m], bfr[n],
                                                              acc[m][n], 0, 0, 0);
    }
    __syncthreads();
  }

#pragma unroll
  for (int n = 0; n < 2; ++n) {
    const int col = bn * 64 + wn * 32 + n * 16 + (lane & 15);
    const float bv = bias[col];
#pragma unroll
    for (int m = 0; m < 2; ++m) {
      const int rbase = bm * 64 + wm * 32 + m * 16 + (lane >> 4) * 4;
#pragma unroll
      for (int j = 0; j < 4; ++j)
        C[(size_t)(rbase + j) * Nc + col] = (bf16_t)(acc[m][n][j] + bv);
    }
  }
}

// --------------------------------------------------------------------- scan
__global__ __launch_bounds__(256) void k_scan(const bf16_t* __restrict__ u,
                                              const float* __restrict__ log_decay,
                                              bf16_t* __restrict__ states) {
  const int n = threadIdx.x;
  const int c = blockIdx.x;
  const int b = blockIdx.y;
  const float decay = 1.0f / (1.0f + __expf(-log_decay[n]));
  const bf16_t* up = u + (size_t)b * 4096 * 256 + n;
  bf16_t* sp = states + (size_t)b * 4096 * 256 + n;
  const int t0 = c * 64;
  const int tb = (c == 0) ? 0 : t0 - 64;
  const int te = t0 + 64;
  float state = 0.0f;
  for (int tblk = tb; tblk < te; tblk += 8) {
    float v[8];
#pragma unroll
    for (int q = 0; q < 8; ++q) v[q] = (float)up[(size_t)(tblk + q) * 256];
#pragma unroll
    for (int q = 0; q < 8; ++q) {
      state = fmaf(decay, state, v[q]);
      if (tblk + q >= t0) sp[(size_t)(tblk + q) * 256] = (bf16_t)state;
    }
  }
}

// -------------------------------------------------------------- fused GEMM2
// out = St@Wo^T (K=256) + X@Wsk^T (K=1024) + tokens + b_out + b_skip
// R6 winner, verbatim (63.5 µs): m97-faithful 128x128, 4 waves, single-buffer
// 32 KiB, compiler-scheduled, plain __syncthreads, involution swizzle,
// 1024 blocks (4/CU — inter-block TLP covers the barrier drain).
__global__ __launch_bounds__(256) void k_gemm2(const bf16_t* __restrict__ St,
                                               const bf16_t* __restrict__ X,
                                               const bf16_t* __restrict__ Wo,
                                               const bf16_t* __restrict__ Wsk,
                                               const float* __restrict__ tokens,
                                               const float* __restrict__ b_out,
                                               const float* __restrict__ b_skip,
                                               float* __restrict__ out) {
  __shared__ __align__(16) bf16_t sA[128 * 64];
  __shared__ __align__(16) bf16_t sB[128 * 64];
  const int tid = threadIdx.x;
  const int lane = tid & 63;
  const int w = tid >> 6;
  const int wm = w >> 1, wn = w & 1;

  const int bid = blockIdx.x;
  const int swz = (bid & 7) * 128 + (bid >> 3);
  const int bm = swz >> 3;    // 0..127
  const int bn = swz & 7;     // 0..7

  const int st_row = tid >> 3;
  const int st_col = ((tid & 7) ^ ((tid >> 3) & 7)) * 8;
  const int lds_off = tid * 8;

  f32x4 acc[4][4] = {};

  for (int kt = 0; kt < 20; ++kt) {
    const bf16_t* Ab;
    const bf16_t* Bb;
    int ld, kb;
    if (kt < 4) { Ab = St; Bb = Wo;  ld = 256;  kb = kt * 64; }
    else        { Ab = X;  Bb = Wsk; ld = 1024; kb = (kt - 4) * 64; }
#pragma unroll
    for (int it = 0; it < 4; ++it)
      ASYNC_COPY16(Ab + (size_t)(bm * 128 + it * 32 + st_row) * ld + kb + st_col,
                   &sA[it * 2048 + lds_off]);
#pragma unroll
    for (int it = 0; it < 4; ++it)
      ASYNC_COPY16(Bb + (size_t)(bn * 128 + it * 32 + st_row) * ld + kb + st_col,
                   &sB[it * 2048 + lds_off]);
    __syncthreads();

#pragma unroll
    for (int kk = 0; kk < 2; ++kk) {
      const int slot = ((kk * 4 + (lane >> 4)) ^ (lane & 7)) * 8;
      bf16x8 af[4], bfr[4];
#pragma unroll
      for (int m = 0; m < 4; ++m)
        af[m] = *(const bf16x8*)&sA[(wm * 64 + m * 16 + (lane & 15)) * 64 + slot];
#pragma unroll
      for (int n = 0; n < 4; ++n)
        bfr[n] = *(const bf16x8*)&sB[(wn * 64 + n * 16 + (lane & 15)) * 64 + slot];
#pragma unroll
      for (int m = 0; m < 4; ++m)
#pragma unroll
        for (int n = 0; n < 4; ++n)
          acc[m][n] = __builtin_amdgcn_mfma_f32_16x16x32_bf16(af[m], bfr[n],
                                                              acc[m][n], 0, 0, 0);
    }
    __syncthreads();
  }

#pragma unroll
  for (int n = 0; n < 4; ++n) {
    const int col = bn * 128 + wn * 64 + n * 16 + (lane & 15);
    const float bv = b_out[col] + b_skip[col];
#pragma unroll
    for (int m = 0; m < 4; ++m) {
      const int rbase = bm * 128 + wm * 64 + m * 16 + (lane >> 4) * 4;
#pragma unroll
      for (int j = 0; j < 4; ++j) {
        const size_t idx = (size_t)(rbase + j) * 1024 + col;
        out[idx] = acc[m][n][j] + tokens[idx] + bv;
      }
    }
  }
}

// ------------------------------------------------------------------ launch
extern "C" void kernel_launch(void* const* d_in, const int* in_sizes, int n_in,
                              void* d_out, int out_size, void* d_ws, size_t ws_size,
                              hipStream_t stream) {
  const float* tokens  = (const float*)d_in[0];
  const float* norm_w  = (const float*)d_in[1];
  const float* W_in    = (const float*)d_in[2];
  const float* b_in    = (const float*)d_in[3];
  const float* W_out   = (const float*)d_in[4];
  const float* b_out   = (const float*)d_in[5];
  const float* W_skip  = (const float*)d_in[6];
  const float* b_skip  = (const float*)d_in[7];
  const float* log_dec = (const float*)d_in[8];
  float* out = (float*)d_out;

  char* w = (char*)d_ws;
  bf16_t* xb  = (bf16_t*)(w);                       // 32 MiB
  bf16_t* u   = (bf16_t*)(w + 33554432ull);         //  8 MiB
  bf16_t* st  = (bf16_t*)(w + 41943040ull);         //  8 MiB
  bf16_t* Wi  = (bf16_t*)(w + 50331648ull);
  bf16_t* Wo  = (bf16_t*)(w + 50855936ull);
  bf16_t* Wsk = (bf16_t*)(w + 51380224ull);

  k_prep<<<dim3(5632), 256, 0, stream>>>(tokens, norm_w, xb, W_in, Wi,
                                         W_out, Wo, W_skip, Wsk);

  k_gemm1<<<dim3(1024), 256, 0, stream>>>(xb, Wi, b_in, u);

  k_scan<<<dim3(64, 4), 256, 0, stream>>>(u, log_dec, st);

  k_gemm2<<<dim3(1024), 256, 0, stream>>>(st, xb, Wo, Wsk, tokens, b_out,
                                          b_skip, out);
}